// Round 3
// baseline (191.210 us; speedup 1.0000x reference)
//
#include <hip/hip_runtime.h>
#include <hip/hip_bf16.h>

// Chamfer loss, N=8, V=4096, C=3, fp32.
// loss = (sum over all 2*N*V points of sqrt(min squared dist to other set)) / (N*V)
//
// Structure (round 3): 2 kernels, no workspace-min, no atomics.
//  - chamfer_main: 512 blocks x 256 thr. Each block: one (dir, n, 128-point
//    A-slice); stages the FULL opposing set B (4096 pts) in LDS as float4
//    (coords + norm). Two threads per A-point, each scans half of B
//    (4 VALU ops/pair: 3 fma + min; A-norm hoisted out of the loop),
//    combined with one shfl_xor. Block writes ONE partial sum (plain store).
//  - chamfer_final: 1 block sums the 512 partials into d_out.

#define N_BATCH 8
#define V 4096
#define TPB 256
#define PPB 128                    // A-points per block (2 threads/point)
#define NVB (V / PPB)              // 32
#define NPTS (N_BATCH * V)         // 32768
#define NBLK (2 * N_BATCH * NVB)   // 512

__global__ __launch_bounds__(TPB) void chamfer_main(const float* __restrict__ x,
                                                    const float* __restrict__ y,
                                                    float* __restrict__ partial) {
    __shared__ float4 sb[V];          // 64 KB: (bx, by, bz, ||b||^2)
    __shared__ float swsum[TPB / 64];

    int bid = blockIdx.x;
    int vb  = bid & (NVB - 1);        // 0..31
    int n   = (bid >> 5) & 7;         // 0..7
    int dir = bid >> 8;               // 0: A=x,B=y ; 1: A=y,B=x

    const float* A  = dir ? y : x;
    const float* B  = dir ? x : y;
    const float* Ab = A + (size_t)n * (V * 3);
    const float* Bb = B + (size_t)n * (V * 3);

    // Stage full B into LDS (48 KB read, L2-resident)
    for (int i = threadIdx.x; i < V; i += TPB) {
        float b0 = Bb[3 * i + 0];
        float b1 = Bb[3 * i + 1];
        float b2 = Bb[3 * i + 2];
        sb[i] = make_float4(b0, b1, b2, b0 * b0 + b1 * b1 + b2 * b2);
    }

    // A-point for this thread (2 threads share one point)
    int p = vb * PPB + (threadIdx.x >> 1);
    const float* ap = Ab + 3 * p;
    float a0 = ap[0], a1 = ap[1], a2 = ap[2];
    float nx0 = -2.0f * a0, nx1 = -2.0f * a1, nx2 = -2.0f * a2;
    float pxs = a0 * a0 + a1 * a1 + a2 * a2;   // hoisted out of the min

    __syncthreads();

    // Each thread scans half of B: 2048 iters x 4 VALU ops.
    // LDS reads are 2-address broadcasts (lane parity) -> conflict-free.
    int j0 = (threadIdx.x & 1) << 11;  // 0 or 2048
    float m = 1e30f;
#pragma unroll 8
    for (int j = j0; j < j0 + 2048; ++j) {
        float4 bv = sb[j];
        float t = fmaf(nx0, bv.x, bv.w);
        t = fmaf(nx1, bv.y, t);
        t = fmaf(nx2, bv.z, t);
        m = fminf(m, t);
    }

    // combine the two halves (adjacent lanes), add hoisted norm, sqrt.
    m = fminf(m, __shfl_xor(m, 1));
    // both lanes of a pair now hold the same min -> weight by 0.5
    float d = 0.5f * sqrtf(fmaxf(m + pxs, 0.0f));

    // block-level sum -> one partial per block (plain store, no init needed)
    for (int off = 32; off > 0; off >>= 1) d += __shfl_down(d, off);
    int lane = threadIdx.x & 63, wid = threadIdx.x >> 6;
    if (lane == 0) swsum[wid] = d;
    __syncthreads();
    if (threadIdx.x == 0) {
        partial[blockIdx.x] = swsum[0] + swsum[1] + swsum[2] + swsum[3];
    }
}

__global__ __launch_bounds__(256) void chamfer_final(const float* __restrict__ partial,
                                                     float* __restrict__ out) {
    __shared__ float ssum[4];
    float s = partial[threadIdx.x] + partial[threadIdx.x + 256];
    for (int off = 32; off > 0; off >>= 1) s += __shfl_down(s, off);
    int lane = threadIdx.x & 63, wid = threadIdx.x >> 6;
    if (lane == 0) ssum[wid] = s;
    __syncthreads();
    if (threadIdx.x == 0) {
        out[0] = (ssum[0] + ssum[1] + ssum[2] + ssum[3]) * (1.0f / (float)NPTS);
    }
}

extern "C" void kernel_launch(void* const* d_in, const int* in_sizes, int n_in,
                              void* d_out, int out_size, void* d_ws, size_t ws_size,
                              hipStream_t stream) {
    const float* x = (const float*)d_in[0];
    const float* y = (const float*)d_in[1];
    float* out = (float*)d_out;
    float* partial = (float*)d_ws;   // 512 floats; fully overwritten each call

    chamfer_main<<<NBLK, TPB, 0, stream>>>(x, y, partial);
    chamfer_final<<<1, 256, 0, stream>>>(partial, out);
}

// Round 4
// 79.558 us; speedup vs baseline: 2.4034x; 2.4034x over previous
//
#include <hip/hip_runtime.h>
#include <hip/hip_bf16.h>

// Chamfer loss, N=8, V=4096, C=3, fp32.
// loss = (sum over all 2*N*V points of sqrt(min squared dist to other set)) / (N*V)
//
// Round 4 structure: 3 kernels, no atomics, no init.
//  - chamfer_main: 512 blocks = (dir, n, vb, yc). Stages a 512-point B-chunk
//    in LDS as float4 (coords + norm, 8 KB). Each thread owns PX=4 A-points
//    in registers; inner loop is ONE broadcast ds_read_b128 per 16 VALU ops
//    (3 fma + min per pair; A-norm hoisted out of the min). Writes per-chunk
//    minima to a 2 MB plane array in d_ws (plain stores).
//  - chamfer_reduce: 256 blocks; min over 8 chunk planes, sqrt, block-sum.
//  - chamfer_final: 1 block sums 512... (256) partials -> out.

#define N_BATCH 8
#define V 4096
#define TPB 256
#define PX 4                  // A-points per thread
#define VBLK (TPB * PX)       // 1024 A-points per block
#define NVB (V / VBLK)        // 4
#define NYC 8                 // B-chunks
#define YC (V / NYC)          // 512
#define NPTS (N_BATCH * V)    // 32768 per direction
#define TOTPTS (2 * NPTS)     // 65536
#define NBLK_MAIN (2 * N_BATCH * NVB * NYC)  // 512
#define NBLK_RED (TOTPTS / TPB)              // 256

__global__ __launch_bounds__(TPB) void chamfer_main(const float* __restrict__ x,
                                                    const float* __restrict__ y,
                                                    float* __restrict__ wmin2) {
    __shared__ float4 sb[YC];   // 8 KB: (bx, by, bz, ||b||^2)

    int bid = blockIdx.x;
    int yc  = bid & (NYC - 1);        // 0..7
    int vb  = (bid >> 3) & (NVB - 1); // 0..3
    int n   = (bid >> 5) & 7;         // 0..7
    int dir = bid >> 8;               // 0: A=x,B=y ; 1: A=y,B=x

    const float* A  = dir ? y : x;
    const float* B  = dir ? x : y;
    const float* Ab = A + (size_t)n * (V * 3);
    const float* Bb = B + (size_t)n * (V * 3) + (size_t)yc * (YC * 3);

    // Stage B-chunk into LDS
    for (int i = threadIdx.x; i < YC; i += TPB) {
        float b0 = Bb[3 * i + 0];
        float b1 = Bb[3 * i + 1];
        float b2 = Bb[3 * i + 2];
        sb[i] = make_float4(b0, b1, b2, b0 * b0 + b1 * b1 + b2 * b2);
    }

    // Per-thread A-points (pre-scaled by -2; norm hoisted out of the min)
    float nx0[PX], nx1[PX], nx2[PX], pxs[PX], m[PX];
    const int pbase = vb * VBLK + threadIdx.x;
#pragma unroll
    for (int p = 0; p < PX; ++p) {
        const float* ap = Ab + 3 * (pbase + p * TPB);
        float a0 = ap[0], a1 = ap[1], a2 = ap[2];
        nx0[p] = -2.0f * a0;
        nx1[p] = -2.0f * a1;
        nx2[p] = -2.0f * a2;
        pxs[p] = a0 * a0 + a1 * a1 + a2 * a2;
        m[p] = 1e30f;
    }

    __syncthreads();

    // 4 VALU ops/pair; one broadcast ds_read_b128 per 16 VALU ops.
#pragma unroll 4
    for (int j = 0; j < YC; j += 2) {
        float4 b0 = sb[j];
        float4 b1 = sb[j + 1];
#pragma unroll
        for (int p = 0; p < PX; ++p) {
            float t0 = fmaf(nx0[p], b0.x, b0.w);
            t0 = fmaf(nx1[p], b0.y, t0);
            t0 = fmaf(nx2[p], b0.z, t0);
            float t1 = fmaf(nx0[p], b1.x, b1.w);
            t1 = fmaf(nx1[p], b1.y, t1);
            t1 = fmaf(nx2[p], b1.z, t1);
            m[p] = fminf(fminf(m[p], t0), t1);  // hope: v_min3_f32
        }
    }

    // Plane layout: wmin2[yc][gp], gp = dir*32768 + n*4096 + vb*1024 + lp
    float* wout = wmin2 + (size_t)yc * TOTPTS + dir * NPTS + n * V + pbase;
#pragma unroll
    for (int p = 0; p < PX; ++p) {
        wout[p * TPB] = m[p] + pxs[p];   // full squared distance (may be ~-eps)
    }
}

__global__ __launch_bounds__(TPB) void chamfer_reduce(const float* __restrict__ wmin2,
                                                      float* __restrict__ partial) {
    __shared__ float swsum[TPB / 64];
    int gp = blockIdx.x * TPB + threadIdx.x;
    float m = wmin2[gp];
#pragma unroll
    for (int yc = 1; yc < NYC; ++yc) {
        m = fminf(m, wmin2[(size_t)yc * TOTPTS + gp]);
    }
    float d = sqrtf(fmaxf(m, 0.0f));
    for (int off = 32; off > 0; off >>= 1) d += __shfl_down(d, off);
    int lane = threadIdx.x & 63, wid = threadIdx.x >> 6;
    if (lane == 0) swsum[wid] = d;
    __syncthreads();
    if (threadIdx.x == 0) {
        partial[blockIdx.x] = swsum[0] + swsum[1] + swsum[2] + swsum[3];
    }
}

__global__ __launch_bounds__(256) void chamfer_final(const float* __restrict__ partial,
                                                     float* __restrict__ out) {
    __shared__ float ssum[4];
    float s = partial[threadIdx.x];
    for (int off = 32; off > 0; off >>= 1) s += __shfl_down(s, off);
    int lane = threadIdx.x & 63, wid = threadIdx.x >> 6;
    if (lane == 0) ssum[wid] = s;
    __syncthreads();
    if (threadIdx.x == 0) {
        out[0] = (ssum[0] + ssum[1] + ssum[2] + ssum[3]) * (1.0f / (float)NPTS);
    }
}

extern "C" void kernel_launch(void* const* d_in, const int* in_sizes, int n_in,
                              void* d_out, int out_size, void* d_ws, size_t ws_size,
                              hipStream_t stream) {
    const float* x = (const float*)d_in[0];
    const float* y = (const float*)d_in[1];
    float* out = (float*)d_out;
    float* wmin2 = (float*)d_ws;                  // 8 * 65536 floats = 2 MB
    float* partial = wmin2 + (size_t)NYC * TOTPTS; // 256 floats

    chamfer_main<<<NBLK_MAIN, TPB, 0, stream>>>(x, y, wmin2);
    chamfer_reduce<<<NBLK_RED, TPB, 0, stream>>>(wmin2, partial);
    chamfer_final<<<1, 256, 0, stream>>>(partial, out);
}